// Round 4
// baseline (596.408 us; speedup 1.0000x reference)
//
#include <hip/hip_runtime.h>
#include <hip/hip_bf16.h>
#include <hip/hip_cooperative_groups.h>

namespace cg = cooperative_groups;

// Problem constants (match reference)
constexpr int cB  = 8;
constexpr int cS  = 4096;
constexpr int cH  = 768;
constexpr int cNH = 12;
constexpr int cL  = 2;
constexpr int cNS = 64;
constexpr int cDH = 64;
constexpr int cM  = cB * cNS;  // 512 rows of activations
constexpr int cG  = 256;       // cooperative grid size (1 block/CU)

typedef __attribute__((ext_vector_type(8))) short bf16x8;
typedef __attribute__((ext_vector_type(4))) float f32x4;

// Shared-memory union across phases.  Attention is the biggest consumer;
// P overlays the Q tile (written only after all QK^T reads complete), so
// total = 3 * 64*68*4 = 52.2 KB < 64 KB static limit.
union SharedU {
    struct { int cnt; int list[cS]; } p;                       // pool (16.4 KB)
    float T[64][65];                                           // wconv (16.6 KB)
    struct { float QP[64][68]; float Ks[64][68]; float Vt[64][68]; } a;  // attn
};

// ---------------------------------------------------------------------------
// GEMM tile: 64 rows (4 waves x 16) x 32 cols, K=768, bf16 MFMA, direct
// global fragments (A and Wt are L2-resident).  Fragment maps (m89/m91):
// a[j]=A[lane&15][q*8+j], b[j]=Wt[lane&15][q*8+j], D: col=lane&15, row=q*4+r.
// ---------------------------------------------------------------------------
__device__ inline void gemm_tile(const __hip_bfloat16* __restrict__ A,
                                 const __hip_bfloat16* __restrict__ Wt,
                                 const float* __restrict__ bias,
                                 float* __restrict__ C,
                                 int bx, int by, int l15, int q4, int wave,
                                 bool gelu)
{
    int m0 = by * 64 + wave * 16;
    int n0 = bx * 32;
    const __hip_bfloat16* Arow = A  + (size_t)(m0 + l15) * cH + q4 * 8;
    const __hip_bfloat16* Wr0  = Wt + (size_t)(n0 + l15) * cH + q4 * 8;
    const __hip_bfloat16* Wr1  = Wr0 + (size_t)16 * cH;

    f32x4 acc0 = {0.f, 0.f, 0.f, 0.f};
    f32x4 acc1 = {0.f, 0.f, 0.f, 0.f};
    #pragma unroll 8
    for (int k0 = 0; k0 < cH; k0 += 32) {
        bf16x8 a  = *(const bf16x8*)(Arow + k0);
        bf16x8 b0 = *(const bf16x8*)(Wr0 + k0);
        bf16x8 b1 = *(const bf16x8*)(Wr1 + k0);
        acc0 = __builtin_amdgcn_mfma_f32_16x16x32_bf16(a, b0, acc0, 0, 0, 0);
        acc1 = __builtin_amdgcn_mfma_f32_16x16x32_bf16(a, b1, acc1, 0, 0, 0);
    }
    #pragma unroll
    for (int nt = 0; nt < 2; ++nt) {
        const f32x4 acc = nt == 0 ? acc0 : acc1;
        int col = n0 + nt * 16 + l15;
        float bv = bias[col];
        #pragma unroll
        for (int r = 0; r < 4; ++r) {
            float v = acc[r] + bv;
            if (gelu) v = 0.5f * v * (1.0f + erff(v * 0.70710678118654752f));
            C[(size_t)(m0 + q4 * 4 + r) * cH + col] = v;
        }
    }
}

// ---------------------------------------------------------------------------
// Attention item: one (batch, head).  fp32 in LDS, 4x4 microtiles,
// full-row softmax with quad shuffles.  P overlays Q.
// ---------------------------------------------------------------------------
__device__ inline void attn_item(SharedU& sh, const float* __restrict__ qb,
                                 __hip_bfloat16* __restrict__ ctx_bf,
                                 int bh, int tid)
{
    const float* q = qb;
    const float* k = qb + (size_t)cM * cH;
    const float* v = qb + (size_t)2 * cM * cH;
    int b = bh / cNH, hh = bh % cNH;
    size_t base = ((size_t)b * cNS) * cH + hh * cDH;

    for (int i = tid; i < cNS * cDH / 4; i += 256) {
        int r = i >> 4;
        int c = (i & 15) << 2;
        float4 qv = *(const float4*)(q + base + (size_t)r * cH + c);
        float4 kv = *(const float4*)(k + base + (size_t)r * cH + c);
        float4 vv = *(const float4*)(v + base + (size_t)r * cH + c);
        *(float4*)&sh.a.QP[r][c] = qv;
        *(float4*)&sh.a.Ks[r][c] = kv;
        sh.a.Vt[c + 0][r] = vv.x; sh.a.Vt[c + 1][r] = vv.y;
        sh.a.Vt[c + 2][r] = vv.z; sh.a.Vt[c + 3][r] = vv.w;
    }
    __syncthreads();

    int tx = tid & 15, ty = tid >> 4;  // 16 x 16 threads
    float accs[4][4] = {};
    for (int d = 0; d < cDH; d += 4) {
        float4 qv[4], kv[4];
        #pragma unroll
        for (int i = 0; i < 4; ++i) qv[i] = *(const float4*)&sh.a.QP[ty * 4 + i][d];
        #pragma unroll
        for (int j = 0; j < 4; ++j) kv[j] = *(const float4*)&sh.a.Ks[tx + j * 16][d];
        #pragma unroll
        for (int i = 0; i < 4; ++i)
            #pragma unroll
            for (int j = 0; j < 4; ++j)
                accs[i][j] += qv[i].x * kv[j].x + qv[i].y * kv[j].y +
                              qv[i].z * kv[j].z + qv[i].w * kv[j].w;
    }
    __syncthreads();   // all QK^T reads of QP complete before P overlay
    const float scale = 0.125f;  // 1/sqrt(64)
    #pragma unroll
    for (int i = 0; i < 4; ++i)
        #pragma unroll
        for (int j = 0; j < 4; ++j)
            sh.a.QP[ty * 4 + i][tx + j * 16] = accs[i][j] * scale;
    __syncthreads();

    {
        int row = tid >> 2, jq = tid & 3;
        float e[16];
        float m = -1e30f;
        #pragma unroll
        for (int c = 0; c < 16; ++c) { e[c] = sh.a.QP[row][jq * 16 + c]; m = fmaxf(m, e[c]); }
        m = fmaxf(m, __shfl_xor(m, 1));
        m = fmaxf(m, __shfl_xor(m, 2));
        float s = 0.f;
        #pragma unroll
        for (int c = 0; c < 16; ++c) { e[c] = __expf(e[c] - m); s += e[c]; }
        s += __shfl_xor(s, 1);
        s += __shfl_xor(s, 2);
        float inv = 1.0f / s;
        #pragma unroll
        for (int c = 0; c < 16; ++c) sh.a.QP[row][jq * 16 + c] = e[c] * inv;
    }
    __syncthreads();

    float acco[4][4] = {};
    for (int c = 0; c < cNS; c += 4) {
        float4 p4[4], vt4[4];
        #pragma unroll
        for (int i = 0; i < 4; ++i) p4[i] = *(const float4*)&sh.a.QP[ty * 4 + i][c];
        #pragma unroll
        for (int j = 0; j < 4; ++j) vt4[j] = *(const float4*)&sh.a.Vt[tx + j * 16][c];
        #pragma unroll
        for (int i = 0; i < 4; ++i)
            #pragma unroll
            for (int j = 0; j < 4; ++j)
                acco[i][j] += p4[i].x * vt4[j].x + p4[i].y * vt4[j].y +
                              p4[i].z * vt4[j].z + p4[i].w * vt4[j].w;
    }
    #pragma unroll
    for (int i = 0; i < 4; ++i)
        #pragma unroll
        for (int j = 0; j < 4; ++j)
            ctx_bf[base + (size_t)(ty * 4 + i) * cH + tx + j * 16] =
                __float2bfloat16(acco[i][j]);
}

// ---------------------------------------------------------------------------
// Fully fused network: one cooperative launch, grid.sync() between phases.
// ---------------------------------------------------------------------------
__global__ __launch_bounds__(256) void fused_kernel(
    const int* __restrict__ sent_ind, const float* __restrict__ sl,
    const float* __restrict__ Wq, const float* __restrict__ Wk,
    const float* __restrict__ Wv, const float* __restrict__ Wo,
    const float* __restrict__ bq, const float* __restrict__ bk,
    const float* __restrict__ bv, const float* __restrict__ bo,
    const float* __restrict__ ln_g, const float* __restrict__ ln_b,
    __hip_bfloat16* __restrict__ wt, __hip_bfloat16* __restrict__ x_bf,
    __hip_bfloat16* __restrict__ ctx_bf,
    float* __restrict__ qb, float* __restrict__ hb, float* __restrict__ out)
{
    __shared__ SharedU sh;
    __shared__ float red[4];
    cg::grid_group grid = cg::this_grid();
    int tid = threadIdx.x;
    int lane = tid & 63, wave = tid >> 6;
    int l15 = lane & 15, q4 = lane >> 4;

    // ---------------- phase 0: pool (items 0..511) + wconv (512..1663) -----
    for (int it = blockIdx.x; it < cM + 1152; it += cG) {
        __syncthreads();   // protect sh reuse across items
        if (it < cM) {
            int bn = it, b = bn >> 6, n = bn & (cNS - 1);
            if (tid == 0) sh.p.cnt = 0;
            __syncthreads();
            const int* si = sent_ind + (size_t)b * cS;
            for (int s = tid; s < cS; s += 256)
                if (s != 0 && si[s] == n) { int p = atomicAdd(&sh.p.cnt, 1); sh.p.list[p] = s; }
            __syncthreads();
            int c = sh.p.cnt;
            if (tid < 192) {
                const float* bbase = sl + (size_t)b * cS * cH;
                int col = tid * 4;
                float4 a0 = {0.f, 0.f, 0.f, 0.f};
                float4 a1 = {0.f, 0.f, 0.f, 0.f};
                float4 a2 = {0.f, 0.f, 0.f, 0.f};
                float4 a3 = {0.f, 0.f, 0.f, 0.f};
                int i = 0;
                for (; i + 4 <= c; i += 4) {
                    float4 r0 = *(const float4*)(bbase + (size_t)sh.p.list[i + 0] * cH + col);
                    float4 r1 = *(const float4*)(bbase + (size_t)sh.p.list[i + 1] * cH + col);
                    float4 r2 = *(const float4*)(bbase + (size_t)sh.p.list[i + 2] * cH + col);
                    float4 r3 = *(const float4*)(bbase + (size_t)sh.p.list[i + 3] * cH + col);
                    a0.x += r0.x; a0.y += r0.y; a0.z += r0.z; a0.w += r0.w;
                    a1.x += r1.x; a1.y += r1.y; a1.z += r1.z; a1.w += r1.w;
                    a2.x += r2.x; a2.y += r2.y; a2.z += r2.z; a2.w += r2.w;
                    a3.x += r3.x; a3.y += r3.y; a3.z += r3.z; a3.w += r3.w;
                }
                for (; i < c; ++i) {
                    float4 r0 = *(const float4*)(bbase + (size_t)sh.p.list[i] * cH + col);
                    a0.x += r0.x; a0.y += r0.y; a0.z += r0.z; a0.w += r0.w;
                }
                float inv = 1.0f / (float)c;
                __hip_bfloat16* xr = x_bf + (size_t)bn * cH + col;
                xr[0] = __float2bfloat16((a0.x + a1.x + a2.x + a3.x) * inv);
                xr[1] = __float2bfloat16((a0.y + a1.y + a2.y + a3.y) * inv);
                xr[2] = __float2bfloat16((a0.z + a1.z + a2.z + a3.z) * inv);
                xr[3] = __float2bfloat16((a0.w + a1.w + a2.w + a3.w) * inv);
            }
        } else {
            int bi = it - cM;                       // 0..1151 = (12 x 12 x 8)
            int bx = bi % 12, by = (bi / 12) % 12, mat = bi / 144;
            int layer = mat >> 2, which = mat & 3;
            const float* W = (which == 0 ? Wq : which == 1 ? Wk : which == 2 ? Wv : Wo)
                             + (size_t)layer * cH * cH;
            int k0 = by * 64, n0 = bx * 64;
            int r = tid >> 2, cb = (tid & 3) * 16;
            #pragma unroll
            for (int u = 0; u < 4; ++u) {
                float4 w4 = *(const float4*)(W + (size_t)(k0 + r) * cH + n0 + cb + u * 4);
                sh.T[r][cb + u * 4 + 0] = w4.x; sh.T[r][cb + u * 4 + 1] = w4.y;
                sh.T[r][cb + u * 4 + 2] = w4.z; sh.T[r][cb + u * 4 + 3] = w4.w;
            }
            __syncthreads();
            int kk = tid & 63;
            int nb = (tid >> 6) * 16;
            __hip_bfloat16* dst = wt + ((size_t)mat * cH + n0) * cH + k0;
            #pragma unroll
            for (int u = 0; u < 16; ++u) {
                int nn = nb + u;
                dst[(size_t)nn * cH + kk] = __float2bfloat16(sh.T[kk][nn]);
            }
        }
    }
    grid.sync();

    // ---------------- layers ----------------
    for (int layer = 0; layer < cL; ++layer) {
        const __hip_bfloat16* wqkv = wt + (size_t)(layer * 4) * cH * cH;
        const __hip_bfloat16* wto  = wt + (size_t)(layer * 4 + 3) * cH * cH;

        // qkv GEMM: 576 tiles (24 x 8 x 3)
        for (int it = blockIdx.x; it < 576; it += cG) {
            int bx = it % 24, by = (it / 24) % 8, mat = it / 192;
            const __hip_bfloat16* Wt = wqkv + (size_t)mat * cH * cH;
            const float* bias = (mat == 0 ? bq : mat == 1 ? bk : bv) + (size_t)layer * cH;
            gemm_tile(x_bf, Wt, bias, qb + (size_t)mat * cM * cH,
                      bx, by, l15, q4, wave, false);
        }
        grid.sync();

        // attention: 96 items
        for (int it = blockIdx.x; it < cB * cNH; it += cG)
            attn_item(sh, qb, ctx_bf, it, tid);
        grid.sync();

        // O GEMM + GELU: 192 tiles (24 x 8)
        for (int it = blockIdx.x; it < 192; it += cG) {
            int bx = it % 24, by = it / 24;
            gemm_tile(ctx_bf, wto, bo + (size_t)layer * cH, hb,
                      bx, by, l15, q4, wave, true);
        }
        grid.sync();

        // LayerNorm: 512 rows
        const float* g  = ln_g + (size_t)layer * cH;
        const float* bb = ln_b + (size_t)layer * cH;
        float* outf = (layer == cL - 1) ? out : nullptr;
        for (int row = blockIdx.x; row < cM; row += cG) {
            __syncthreads();
            const float* r = hb + (size_t)row * cH;
            float v0 = r[tid], v1 = r[tid + 256], v2 = r[tid + 512];
            float s = v0 + v1 + v2;
            #pragma unroll
            for (int o = 32; o; o >>= 1) s += __shfl_xor(s, o);
            if ((tid & 63) == 0) red[tid >> 6] = s;
            __syncthreads();
            float mu = (red[0] + red[1] + red[2] + red[3]) * (1.0f / 768.0f);
            float d0 = v0 - mu, d1 = v1 - mu, d2 = v2 - mu;
            float ss = d0 * d0 + d1 * d1 + d2 * d2;
            __syncthreads();
            #pragma unroll
            for (int o = 32; o; o >>= 1) ss += __shfl_xor(ss, o);
            if ((tid & 63) == 0) red[tid >> 6] = ss;
            __syncthreads();
            float var = (red[0] + red[1] + red[2] + red[3]) * (1.0f / 768.0f);
            float inv = rsqrtf(var + 1e-12f);
            float o0 = d0 * inv * g[tid]       + bb[tid];
            float o1 = d1 * inv * g[tid + 256] + bb[tid + 256];
            float o2 = d2 * inv * g[tid + 512] + bb[tid + 512];
            __hip_bfloat16* xr = x_bf + (size_t)row * cH;
            xr[tid]       = __float2bfloat16(o0);
            xr[tid + 256] = __float2bfloat16(o1);
            xr[tid + 512] = __float2bfloat16(o2);
            if (outf) {
                float* orow = outf + (size_t)row * cH;
                orow[tid] = o0; orow[tid + 256] = o1; orow[tid + 512] = o2;
            }
        }
        grid.sync();
    }
}

// ---------------------------------------------------------------------------
extern "C" void kernel_launch(void* const* d_in, const int* in_sizes, int n_in,
                              void* d_out, int out_size, void* d_ws, size_t ws_size,
                              hipStream_t stream) {
    const int*   sent_ind = (const int*)d_in[0];
    const float* start    = (const float*)d_in[1];
    const float* Wq = (const float*)d_in[2];
    const float* bq = (const float*)d_in[3];
    const float* Wk = (const float*)d_in[4];
    const float* bk = (const float*)d_in[5];
    const float* Wv = (const float*)d_in[6];
    const float* bv = (const float*)d_in[7];
    const float* Wo = (const float*)d_in[8];
    const float* bo = (const float*)d_in[9];
    const float* ln_g = (const float*)d_in[10];
    const float* ln_b = (const float*)d_in[11];
    float* out = (float*)d_out;

    char* w = (char*)d_ws;
    __hip_bfloat16* wt     = (__hip_bfloat16*)w;                       // 8*H*H bf16
    __hip_bfloat16* x_bf   = (__hip_bfloat16*)(w + 9437184);           // M*H bf16
    __hip_bfloat16* ctx_bf = (__hip_bfloat16*)(w + 9437184 + 786432);
    float* qb = (float*)(w + 9437184 + 2 * 786432);   // [3][M][H] f32 (q,k,v)
    float* hb = qb + (size_t)3 * cM * cH;

    void* args[] = {
        (void*)&sent_ind, (void*)&start,
        (void*)&Wq, (void*)&Wk, (void*)&Wv, (void*)&Wo,
        (void*)&bq, (void*)&bk, (void*)&bv, (void*)&bo,
        (void*)&ln_g, (void*)&ln_b,
        (void*)&wt, (void*)&x_bf, (void*)&ctx_bf,
        (void*)&qb, (void*)&hb, (void*)&out,
    };
    hipLaunchCooperativeKernel((void*)fused_kernel, dim3(cG), dim3(256),
                               args, 0, stream);
}

// Round 5
// 350.273 us; speedup vs baseline: 1.7027x; 1.7027x over previous
//
#include <hip/hip_runtime.h>
#include <hip/hip_bf16.h>

// Problem constants (match reference)
constexpr int cB  = 8;
constexpr int cS  = 4096;
constexpr int cH  = 768;
constexpr int cNH = 12;
constexpr int cL  = 2;
constexpr int cNS = 64;
constexpr int cDH = 64;
constexpr int cM  = cB * cNS;  // 512 rows of activations

typedef __attribute__((ext_vector_type(8))) short bf16x8;
typedef __attribute__((ext_vector_type(4))) float f32x4;

// ---------------------------------------------------------------------------
// 1) Fused prep: blocks [0, 512) segment-mean pooling; blocks [512, 1664)
//    weight transpose+convert wt[mat][n][k] = bf16(W[mat][k][n]).
// ---------------------------------------------------------------------------
union PrepShared {
    float T[64][65];
    struct { int cnt; int list[cS]; } p;
};

__global__ __launch_bounds__(256) void prep_kernel(
    const int* __restrict__ sent_ind, const float* __restrict__ sl,
    __hip_bfloat16* __restrict__ xb,
    const float* __restrict__ Wq, const float* __restrict__ Wk,
    const float* __restrict__ Wv, const float* __restrict__ Wo,
    __hip_bfloat16* __restrict__ wt)
{
    __shared__ PrepShared sh;
    int tid = threadIdx.x;

    if (blockIdx.x < (unsigned)cM) {
        int bn = blockIdx.x;
        int b = bn >> 6, n = bn & (cNS - 1);
        if (tid == 0) sh.p.cnt = 0;
        __syncthreads();
        const int* si = sent_ind + (size_t)b * cS;
        for (int s = tid; s < cS; s += 256)
            if (s != 0 && si[s] == n) { int p = atomicAdd(&sh.p.cnt, 1); sh.p.list[p] = s; }
        __syncthreads();
        int c = sh.p.cnt;
        if (tid < 192) {
            const float* bbase = sl + (size_t)b * cS * cH;
            int col = tid * 4;
            float4 a0 = {0.f, 0.f, 0.f, 0.f};
            float4 a1 = {0.f, 0.f, 0.f, 0.f};
            float4 a2 = {0.f, 0.f, 0.f, 0.f};
            float4 a3 = {0.f, 0.f, 0.f, 0.f};
            int i = 0;
            for (; i + 4 <= c; i += 4) {
                float4 r0 = *(const float4*)(bbase + (size_t)sh.p.list[i + 0] * cH + col);
                float4 r1 = *(const float4*)(bbase + (size_t)sh.p.list[i + 1] * cH + col);
                float4 r2 = *(const float4*)(bbase + (size_t)sh.p.list[i + 2] * cH + col);
                float4 r3 = *(const float4*)(bbase + (size_t)sh.p.list[i + 3] * cH + col);
                a0.x += r0.x; a0.y += r0.y; a0.z += r0.z; a0.w += r0.w;
                a1.x += r1.x; a1.y += r1.y; a1.z += r1.z; a1.w += r1.w;
                a2.x += r2.x; a2.y += r2.y; a2.z += r2.z; a2.w += r2.w;
                a3.x += r3.x; a3.y += r3.y; a3.z += r3.z; a3.w += r3.w;
            }
            for (; i < c; ++i) {
                float4 r0 = *(const float4*)(bbase + (size_t)sh.p.list[i] * cH + col);
                a0.x += r0.x; a0.y += r0.y; a0.z += r0.z; a0.w += r0.w;
            }
            float inv = 1.0f / (float)c;
            __hip_bfloat16* xr = xb + (size_t)bn * cH + col;
            xr[0] = __float2bfloat16((a0.x + a1.x + a2.x + a3.x) * inv);
            xr[1] = __float2bfloat16((a0.y + a1.y + a2.y + a3.y) * inv);
            xr[2] = __float2bfloat16((a0.z + a1.z + a2.z + a3.z) * inv);
            xr[3] = __float2bfloat16((a0.w + a1.w + a2.w + a3.w) * inv);
        }
    } else {
        int bi = blockIdx.x - cM;           // 0..1151 = (12 x 12 x 8)
        int bx = bi % 12, by = (bi / 12) % 12, mat = bi / 144;
        int layer = mat >> 2, which = mat & 3;
        const float* W = (which == 0 ? Wq : which == 1 ? Wk : which == 2 ? Wv : Wo)
                         + (size_t)layer * cH * cH;
        int k0 = by * 64, n0 = bx * 64;
        int r = tid >> 2, cb = (tid & 3) * 16;
        #pragma unroll
        for (int u = 0; u < 4; ++u) {
            float4 w4 = *(const float4*)(W + (size_t)(k0 + r) * cH + n0 + cb + u * 4);
            sh.T[r][cb + u * 4 + 0] = w4.x; sh.T[r][cb + u * 4 + 1] = w4.y;
            sh.T[r][cb + u * 4 + 2] = w4.z; sh.T[r][cb + u * 4 + 3] = w4.w;
        }
        __syncthreads();
        int kk = tid & 63;
        int nb = (tid >> 6) * 16;
        __hip_bfloat16* dst = wt + ((size_t)mat * cH + n0) * cH + k0;
        #pragma unroll
        for (int u = 0; u < 16; ++u) {
            int nn = nb + u;
            dst[(size_t)nn * cH + kk] = __float2bfloat16(sh.T[kk][nn]);
        }
    }
}

// ---------------------------------------------------------------------------
// 2) Fused qkv-GEMM + attention.  One block per (batch, head) = 96 blocks.
//    Block computes q,k,v [64 sentences x 64 dh] for its head via MFMA
//    (K=768, weights from L2) directly into LDS, then runs attention.
//    Wave w handles combos c = w*3+j, c -> (mat=c>>2, nt=c&3), all 4 m-tiles.
//    MFMA maps (m89/m91): a[j]=A[l15][q4*8+j], b[j]=Wt[l15][q4*8+j],
//    D: col=l15, row=q4*4+r.
// ---------------------------------------------------------------------------
struct AttnShared {
    float QP[cNS][cDH + 4];  // Q, later overlaid by P
    float Ks[cNS][cDH + 4];
    float Vt[cDH][cNS + 4];
};

__global__ __launch_bounds__(256) void qkvattn_kernel(
    const __hip_bfloat16* __restrict__ x_bf,
    const __hip_bfloat16* __restrict__ wqkv,   // [3][H][H] bf16 (n-major)
    const float* __restrict__ bq, const float* __restrict__ bk,
    const float* __restrict__ bv,
    __hip_bfloat16* __restrict__ ctx_bf)
{
    __shared__ AttnShared sh;
    int tid = threadIdx.x;
    int lane = tid & 63, wave = tid >> 6;
    int l15 = lane & 15, q4 = lane >> 4;
    int b = blockIdx.x / cNH, hh = blockIdx.x % cNH;

    // ---- GEMM: 12 acc tiles per wave (3 combos x 4 m-tiles) ----
    const __hip_bfloat16* Arow[4];
    #pragma unroll
    for (int m = 0; m < 4; ++m)
        Arow[m] = x_bf + (size_t)(b * 64 + m * 16 + l15) * cH + q4 * 8;
    const __hip_bfloat16* Brow[3];
    int cmat[3], cnt_[3];
    #pragma unroll
    for (int j = 0; j < 3; ++j) {
        int c = wave * 3 + j;
        cmat[j] = c >> 2; cnt_[j] = c & 3;
        Brow[j] = wqkv + (size_t)cmat[j] * cH * cH
                       + (size_t)(hh * 64 + cnt_[j] * 16 + l15) * cH + q4 * 8;
    }

    f32x4 acc[3][4];
    #pragma unroll
    for (int j = 0; j < 3; ++j)
        #pragma unroll
        for (int m = 0; m < 4; ++m) acc[j][m] = (f32x4){0.f, 0.f, 0.f, 0.f};

    #pragma unroll 4
    for (int k0 = 0; k0 < cH; k0 += 32) {
        bf16x8 a[4], bb8[3];
        #pragma unroll
        for (int m = 0; m < 4; ++m) a[m] = *(const bf16x8*)(Arow[m] + k0);
        #pragma unroll
        for (int j = 0; j < 3; ++j) bb8[j] = *(const bf16x8*)(Brow[j] + k0);
        #pragma unroll
        for (int j = 0; j < 3; ++j)
            #pragma unroll
            for (int m = 0; m < 4; ++m)
                acc[j][m] = __builtin_amdgcn_mfma_f32_16x16x32_bf16(a[m], bb8[j], acc[j][m], 0, 0, 0);
    }

    // ---- epilogue into LDS ----
    const float scale = 0.125f;  // 1/sqrt(64)
    #pragma unroll
    for (int j = 0; j < 3; ++j) {
        int mat = cmat[j], nt = cnt_[j];
        int col_d = nt * 16 + l15;
        int col_g = hh * 64 + col_d;
        float bias = (mat == 0 ? bq : mat == 1 ? bk : bv)[col_g];
        #pragma unroll
        for (int m = 0; m < 4; ++m) {
            #pragma unroll
            for (int r = 0; r < 4; ++r) {
                int row_s = m * 16 + q4 * 4 + r;
                float v = acc[j][m][r] + bias;
                if (mat == 0)      sh.QP[row_s][col_d] = v * scale;
                else if (mat == 1) sh.Ks[row_s][col_d] = v;
                else               sh.Vt[col_d][row_s] = v;
            }
        }
    }
    __syncthreads();

    // ---- attention (16x16 threads, 4x4 microtiles) ----
    int tx = tid & 15, ty = tid >> 4;
    float accs[4][4] = {};
    for (int d = 0; d < cDH; d += 4) {
        float4 qv[4], kv[4];
        #pragma unroll
        for (int i = 0; i < 4; ++i) qv[i] = *(const float4*)&sh.QP[ty * 4 + i][d];
        #pragma unroll
        for (int j = 0; j < 4; ++j) kv[j] = *(const float4*)&sh.Ks[tx + j * 16][d];
        #pragma unroll
        for (int i = 0; i < 4; ++i)
            #pragma unroll
            for (int j = 0; j < 4; ++j)
                accs[i][j] += qv[i].x * kv[j].x + qv[i].y * kv[j].y +
                              qv[i].z * kv[j].z + qv[i].w * kv[j].w;
    }
    __syncthreads();   // all QK^T reads done before P overlays Q
    #pragma unroll
    for (int i = 0; i < 4; ++i)
        #pragma unroll
        for (int j = 0; j < 4; ++j)
            sh.QP[ty * 4 + i][tx + j * 16] = accs[i][j];
    __syncthreads();

    {   // softmax: row = tid>>2, 16 cols/thread, quad shuffle
        int row = tid >> 2, jq = tid & 3;
        float e[16];
        float m = -1e30f;
        #pragma unroll
        for (int c = 0; c < 16; ++c) { e[c] = sh.QP[row][jq * 16 + c]; m = fmaxf(m, e[c]); }
        m = fmaxf(m, __shfl_xor(m, 1));
        m = fmaxf(m, __shfl_xor(m, 2));
        float s = 0.f;
        #pragma unroll
        for (int c = 0; c < 16; ++c) { e[c] = __expf(e[c] - m); s += e[c]; }
        s += __shfl_xor(s, 1);
        s += __shfl_xor(s, 2);
        float inv = 1.0f / s;
        #pragma unroll
        for (int c = 0; c < 16; ++c) sh.QP[row][jq * 16 + c] = e[c] * inv;
    }
    __syncthreads();

    float acco[4][4] = {};
    for (int c = 0; c < cNS; c += 4) {
        float4 p4[4], vt4[4];
        #pragma unroll
        for (int i = 0; i < 4; ++i) p4[i] = *(const float4*)&sh.QP[ty * 4 + i][c];
        #pragma unroll
        for (int j = 0; j < 4; ++j) vt4[j] = *(const float4*)&sh.Vt[tx + j * 16][c];
        #pragma unroll
        for (int i = 0; i < 4; ++i)
            #pragma unroll
            for (int j = 0; j < 4; ++j)
                acco[i][j] += p4[i].x * vt4[j].x + p4[i].y * vt4[j].y +
                              p4[i].z * vt4[j].z + p4[i].w * vt4[j].w;
    }
    size_t base = ((size_t)b * cNS) * cH + hh * cDH;
    #pragma unroll
    for (int i = 0; i < 4; ++i)
        #pragma unroll
        for (int j = 0; j < 4; ++j)
            ctx_bf[base + (size_t)(ty * 4 + i) * cH + tx + j * 16] =
                __float2bfloat16(acco[i][j]);
}

// ---------------------------------------------------------------------------
// 3) Fused O-GEMM + GELU + LayerNorm.  32 blocks x 16 rows x 768 cols.
//    Wave w: cols [w*192, w*192+192) = 12 n-tiles (48 acc VGPRs); full rows
//    stay in registers so LN reduces in-wave (shfl) + cross-wave (LDS).
// ---------------------------------------------------------------------------
__global__ __launch_bounds__(256) void oln_kernel(
    const __hip_bfloat16* __restrict__ ctx_bf,
    const __hip_bfloat16* __restrict__ wto,    // [H][H] bf16 n-major
    const float* __restrict__ bo,
    const float* __restrict__ g, const float* __restrict__ bb,
    __hip_bfloat16* __restrict__ xb, float* __restrict__ outf)
{
    __shared__ float part[4][16][2];
    int tid = threadIdx.x;
    int lane = tid & 63, wave = tid >> 6;
    int l15 = lane & 15, q4 = lane >> 4;
    int r0 = blockIdx.x * 16;

    const __hip_bfloat16* Arow = ctx_bf + (size_t)(r0 + l15) * cH + q4 * 8;
    const __hip_bfloat16* Brow[12];
    #pragma unroll
    for (int nt = 0; nt < 12; ++nt)
        Brow[nt] = wto + (size_t)(wave * 192 + nt * 16 + l15) * cH + q4 * 8;

    f32x4 acc[12];
    #pragma unroll
    for (int nt = 0; nt < 12; ++nt) acc[nt] = (f32x4){0.f, 0.f, 0.f, 0.f};

    #pragma unroll 2
    for (int k0 = 0; k0 < cH; k0 += 32) {
        bf16x8 a = *(const bf16x8*)(Arow + k0);
        #pragma unroll
        for (int nt = 0; nt < 12; ++nt) {
            bf16x8 b8 = *(const bf16x8*)(Brow[nt] + k0);
            acc[nt] = __builtin_amdgcn_mfma_f32_16x16x32_bf16(a, b8, acc[nt], 0, 0, 0);
        }
    }

    // bias + GELU in place; accumulate row sums/sumsq
    float rs[4] = {0.f, 0.f, 0.f, 0.f}, rq[4] = {0.f, 0.f, 0.f, 0.f};
    #pragma unroll
    for (int nt = 0; nt < 12; ++nt) {
        int col = wave * 192 + nt * 16 + l15;
        float bv = bo[col];
        #pragma unroll
        for (int r = 0; r < 4; ++r) {
            float v = acc[nt][r] + bv;
            v = 0.5f * v * (1.0f + erff(v * 0.70710678118654752f));
            acc[nt][r] = v;
            rs[r] += v;
            rq[r] += v * v;
        }
    }
    // in-wave reduce over l15 (lanes q4*16 + l15)
    #pragma unroll
    for (int o = 8; o; o >>= 1) {
        #pragma unroll
        for (int r = 0; r < 4; ++r) {
            rs[r] += __shfl_xor(rs[r], o);
            rq[r] += __shfl_xor(rq[r], o);
        }
    }
    if (l15 == 0) {
        #pragma unroll
        for (int r = 0; r < 4; ++r) {
            part[wave][q4 * 4 + r][0] = rs[r];
            part[wave][q4 * 4 + r][1] = rq[r];
        }
    }
    __syncthreads();
    #pragma unroll
    for (int r = 0; r < 4; ++r) {
        int row = q4 * 4 + r;
        float S  = part[0][row][0] + part[1][row][0] + part[2][row][0] + part[3][row][0];
        float Q2 = part[0][row][1] + part[1][row][1] + part[2][row][1] + part[3][row][1];
        float mu  = S * (1.0f / 768.0f);
        float var = Q2 * (1.0f / 768.0f) - mu * mu;
        float inv = rsqrtf(var + 1e-12f);
        int row_g = r0 + row;
        #pragma unroll
        for (int nt = 0; nt < 12; ++nt) {
            int col = wave * 192 + nt * 16 + l15;
            float o = (acc[nt][r] - mu) * inv * g[col] + bb[col];
            xb[(size_t)row_g * cH + col] = __float2bfloat16(o);
            if (outf) outf[(size_t)row_g * cH + col] = o;
        }
    }
}

// ---------------------------------------------------------------------------
extern "C" void kernel_launch(void* const* d_in, const int* in_sizes, int n_in,
                              void* d_out, int out_size, void* d_ws, size_t ws_size,
                              hipStream_t stream) {
    const int*   sent_ind = (const int*)d_in[0];
    const float* start    = (const float*)d_in[1];
    const float* Wq = (const float*)d_in[2];
    const float* bq = (const float*)d_in[3];
    const float* Wk = (const float*)d_in[4];
    const float* bk = (const float*)d_in[5];
    const float* Wv = (const float*)d_in[6];
    const float* bv = (const float*)d_in[7];
    const float* Wo = (const float*)d_in[8];
    const float* bo = (const float*)d_in[9];
    const float* ln_g = (const float*)d_in[10];
    const float* ln_b = (const float*)d_in[11];
    float* out = (float*)d_out;

    char* w = (char*)d_ws;
    __hip_bfloat16* wt     = (__hip_bfloat16*)w;                 // 8*H*H bf16
    __hip_bfloat16* x_bf   = (__hip_bfloat16*)(w + 9437184);     // M*H bf16
    __hip_bfloat16* ctx_bf = (__hip_bfloat16*)(w + 9437184 + 786432);

    prep_kernel<<<cM + 1152, 256, 0, stream>>>(sent_ind, start, x_bf,
                                               Wq, Wk, Wv, Wo, wt);

    for (int i = 0; i < cL; ++i) {
        const __hip_bfloat16* wqkv = wt + (size_t)(i * 4) * cH * cH;     // q,k,v contiguous
        const __hip_bfloat16* wto  = wt + (size_t)(i * 4 + 3) * cH * cH;
        qkvattn_kernel<<<cB * cNH, 256, 0, stream>>>(
            x_bf, wqkv, bq + (size_t)i * cH, bk + (size_t)i * cH, bv + (size_t)i * cH,
            ctx_bf);
        oln_kernel<<<cM / 16, 256, 0, stream>>>(
            ctx_bf, wto, bo + (size_t)i * cH,
            ln_g + (size_t)i * cH, ln_b + (size_t)i * cH,
            x_bf, (i == cL - 1) ? out : nullptr);
    }
}

// Round 6
// 287.201 us; speedup vs baseline: 2.0766x; 1.2196x over previous
//
#include <hip/hip_runtime.h>
#include <hip/hip_bf16.h>

// Problem constants (match reference)
constexpr int cB  = 8;
constexpr int cS  = 4096;
constexpr int cH  = 768;
constexpr int cNH = 12;
constexpr int cL  = 2;
constexpr int cNS = 64;
constexpr int cDH = 64;
constexpr int cM  = cB * cNS;  // 512 rows of activations

typedef __attribute__((ext_vector_type(8))) short bf16x8;
typedef __attribute__((ext_vector_type(4))) float f32x4;

// ---------------------------------------------------------------------------
// 1) Fused prep: blocks [0, 512) segment-mean pooling; blocks [512, 1664)
//    weight transpose+convert wt[mat][n][k] = bf16(W[mat][k][n]).
// ---------------------------------------------------------------------------
union PrepShared {
    float T[64][65];
    struct { int cnt; int list[cS]; } p;
};

__global__ __launch_bounds__(256) void prep_kernel(
    const int* __restrict__ sent_ind, const float* __restrict__ sl,
    __hip_bfloat16* __restrict__ xb,
    const float* __restrict__ Wq, const float* __restrict__ Wk,
    const float* __restrict__ Wv, const float* __restrict__ Wo,
    __hip_bfloat16* __restrict__ wt)
{
    __shared__ PrepShared sh;
    int tid = threadIdx.x;

    if (blockIdx.x < (unsigned)cM) {
        int bn = blockIdx.x;
        int b = bn >> 6, n = bn & (cNS - 1);
        if (tid == 0) sh.p.cnt = 0;
        __syncthreads();
        const int* si = sent_ind + (size_t)b * cS;
        for (int s = tid; s < cS; s += 256)
            if (s != 0 && si[s] == n) { int p = atomicAdd(&sh.p.cnt, 1); sh.p.list[p] = s; }
        __syncthreads();
        int c = sh.p.cnt;
        if (tid < 192) {
            const float* bbase = sl + (size_t)b * cS * cH;
            int col = tid * 4;
            float4 a0 = {0.f, 0.f, 0.f, 0.f};
            float4 a1 = {0.f, 0.f, 0.f, 0.f};
            float4 a2 = {0.f, 0.f, 0.f, 0.f};
            float4 a3 = {0.f, 0.f, 0.f, 0.f};
            int i = 0;
            for (; i + 4 <= c; i += 4) {
                float4 r0 = *(const float4*)(bbase + (size_t)sh.p.list[i + 0] * cH + col);
                float4 r1 = *(const float4*)(bbase + (size_t)sh.p.list[i + 1] * cH + col);
                float4 r2 = *(const float4*)(bbase + (size_t)sh.p.list[i + 2] * cH + col);
                float4 r3 = *(const float4*)(bbase + (size_t)sh.p.list[i + 3] * cH + col);
                a0.x += r0.x; a0.y += r0.y; a0.z += r0.z; a0.w += r0.w;
                a1.x += r1.x; a1.y += r1.y; a1.z += r1.z; a1.w += r1.w;
                a2.x += r2.x; a2.y += r2.y; a2.z += r2.z; a2.w += r2.w;
                a3.x += r3.x; a3.y += r3.y; a3.z += r3.z; a3.w += r3.w;
            }
            for (; i < c; ++i) {
                float4 r0 = *(const float4*)(bbase + (size_t)sh.p.list[i] * cH + col);
                a0.x += r0.x; a0.y += r0.y; a0.z += r0.z; a0.w += r0.w;
            }
            float inv = 1.0f / (float)c;
            __hip_bfloat16* xr = xb + (size_t)bn * cH + col;
            xr[0] = __float2bfloat16((a0.x + a1.x + a2.x + a3.x) * inv);
            xr[1] = __float2bfloat16((a0.y + a1.y + a2.y + a3.y) * inv);
            xr[2] = __float2bfloat16((a0.z + a1.z + a2.z + a3.z) * inv);
            xr[3] = __float2bfloat16((a0.w + a1.w + a2.w + a3.w) * inv);
        }
    } else {
        int bi = blockIdx.x - cM;           // 0..1151 = (12 x 12 x 8)
        int bx = bi % 12, by = (bi / 12) % 12, mat = bi / 144;
        int layer = mat >> 2, which = mat & 3;
        const float* W = (which == 0 ? Wq : which == 1 ? Wk : which == 2 ? Wv : Wo)
                         + (size_t)layer * cH * cH;
        int k0 = by * 64, n0 = bx * 64;
        int r = tid >> 2, cb = (tid & 3) * 16;
        #pragma unroll
        for (int u = 0; u < 4; ++u) {
            float4 w4 = *(const float4*)(W + (size_t)(k0 + r) * cH + n0 + cb + u * 4);
            sh.T[r][cb + u * 4 + 0] = w4.x; sh.T[r][cb + u * 4 + 1] = w4.y;
            sh.T[r][cb + u * 4 + 2] = w4.z; sh.T[r][cb + u * 4 + 3] = w4.w;
        }
        __syncthreads();
        int kk = tid & 63;
        int nb = (tid >> 6) * 16;
        __hip_bfloat16* dst = wt + ((size_t)mat * cH + n0) * cH + k0;
        #pragma unroll
        for (int u = 0; u < 16; ++u) {
            int nn = nb + u;
            dst[(size_t)nn * cH + kk] = __float2bfloat16(sh.T[kk][nn]);
        }
    }
}

// ---------------------------------------------------------------------------
// 2) Fused qkv-GEMM + attention.  One block per (batch, head) = 96 blocks.
//    Block computes q,k,v [64 x 64] for its head via MFMA (K=768, weights
//    L2-resident, ~0.4 MB/block) straight into LDS, then runs attention.
//    Wave w: combos c = w*3+j -> (mat=c>>2, nt=c&3), all 4 m-tiles.
//    MFMA maps (m89/m91): a[j]=A[l15][q4*8+j], b[j]=Wt[l15][q4*8+j],
//    D: col=l15, row=q4*4+r.
// ---------------------------------------------------------------------------
struct AttnShared {
    float QP[cNS][cDH + 4];  // Q, later overlaid by P
    float Ks[cNS][cDH + 4];
    float Vt[cDH][cNS + 4];
};

__global__ __launch_bounds__(256) void qkvattn_kernel(
    const __hip_bfloat16* __restrict__ x_bf,
    const __hip_bfloat16* __restrict__ wqkv,   // [3][H][H] bf16 (n-major)
    const float* __restrict__ bq, const float* __restrict__ bk,
    const float* __restrict__ bv,
    __hip_bfloat16* __restrict__ ctx_bf)
{
    __shared__ AttnShared sh;
    int tid = threadIdx.x;
    int lane = tid & 63, wave = tid >> 6;
    int l15 = lane & 15, q4 = lane >> 4;
    int b = blockIdx.x / cNH, hh = blockIdx.x % cNH;

    const __hip_bfloat16* Arow[4];
    #pragma unroll
    for (int m = 0; m < 4; ++m)
        Arow[m] = x_bf + (size_t)(b * 64 + m * 16 + l15) * cH + q4 * 8;
    const __hip_bfloat16* Brow[3];
    int cmat[3], cnt_[3];
    #pragma unroll
    for (int j = 0; j < 3; ++j) {
        int c = wave * 3 + j;
        cmat[j] = c >> 2; cnt_[j] = c & 3;
        Brow[j] = wqkv + (size_t)cmat[j] * cH * cH
                       + (size_t)(hh * 64 + cnt_[j] * 16 + l15) * cH + q4 * 8;
    }

    f32x4 acc[3][4];
    #pragma unroll
    for (int j = 0; j < 3; ++j)
        #pragma unroll
        for (int m = 0; m < 4; ++m) acc[j][m] = (f32x4){0.f, 0.f, 0.f, 0.f};

    #pragma unroll 4
    for (int k0 = 0; k0 < cH; k0 += 32) {
        bf16x8 a[4], bb8[3];
        #pragma unroll
        for (int m = 0; m < 4; ++m) a[m] = *(const bf16x8*)(Arow[m] + k0);
        #pragma unroll
        for (int j = 0; j < 3; ++j) bb8[j] = *(const bf16x8*)(Brow[j] + k0);
        #pragma unroll
        for (int j = 0; j < 3; ++j)
            #pragma unroll
            for (int m = 0; m < 4; ++m)
                acc[j][m] = __builtin_amdgcn_mfma_f32_16x16x32_bf16(a[m], bb8[j], acc[j][m], 0, 0, 0);
    }

    const float scale = 0.125f;  // 1/sqrt(64)
    #pragma unroll
    for (int j = 0; j < 3; ++j) {
        int mat = cmat[j], nt = cnt_[j];
        int col_d = nt * 16 + l15;
        int col_g = hh * 64 + col_d;
        float bias = (mat == 0 ? bq : mat == 1 ? bk : bv)[col_g];
        #pragma unroll
        for (int m = 0; m < 4; ++m) {
            #pragma unroll
            for (int r = 0; r < 4; ++r) {
                int row_s = m * 16 + q4 * 4 + r;
                float v = acc[j][m][r] + bias;
                if (mat == 0)      sh.QP[row_s][col_d] = v * scale;
                else if (mat == 1) sh.Ks[row_s][col_d] = v;
                else               sh.Vt[col_d][row_s] = v;
            }
        }
    }
    __syncthreads();

    int tx = tid & 15, ty = tid >> 4;  // 16x16 threads, 4x4 microtiles
    float accs[4][4] = {};
    for (int d = 0; d < cDH; d += 4) {
        float4 qv[4], kv[4];
        #pragma unroll
        for (int i = 0; i < 4; ++i) qv[i] = *(const float4*)&sh.QP[ty * 4 + i][d];
        #pragma unroll
        for (int j = 0; j < 4; ++j) kv[j] = *(const float4*)&sh.Ks[tx + j * 16][d];
        #pragma unroll
        for (int i = 0; i < 4; ++i)
            #pragma unroll
            for (int j = 0; j < 4; ++j)
                accs[i][j] += qv[i].x * kv[j].x + qv[i].y * kv[j].y +
                              qv[i].z * kv[j].z + qv[i].w * kv[j].w;
    }
    __syncthreads();   // all QK^T reads done before P overlays Q
    #pragma unroll
    for (int i = 0; i < 4; ++i)
        #pragma unroll
        for (int j = 0; j < 4; ++j)
            sh.QP[ty * 4 + i][tx + j * 16] = accs[i][j];
    __syncthreads();

    {   // softmax: row = tid>>2, 16 cols/thread, quad shuffle
        int row = tid >> 2, jq = tid & 3;
        float e[16];
        float m = -1e30f;
        #pragma unroll
        for (int c = 0; c < 16; ++c) { e[c] = sh.QP[row][jq * 16 + c]; m = fmaxf(m, e[c]); }
        m = fmaxf(m, __shfl_xor(m, 1));
        m = fmaxf(m, __shfl_xor(m, 2));
        float s = 0.f;
        #pragma unroll
        for (int c = 0; c < 16; ++c) { e[c] = __expf(e[c] - m); s += e[c]; }
        s += __shfl_xor(s, 1);
        s += __shfl_xor(s, 2);
        float inv = 1.0f / s;
        #pragma unroll
        for (int c = 0; c < 16; ++c) sh.QP[row][jq * 16 + c] = e[c] * inv;
    }
    __syncthreads();

    float acco[4][4] = {};
    for (int c = 0; c < cNS; c += 4) {
        float4 p4[4], vt4[4];
        #pragma unroll
        for (int i = 0; i < 4; ++i) p4[i] = *(const float4*)&sh.QP[ty * 4 + i][c];
        #pragma unroll
        for (int j = 0; j < 4; ++j) vt4[j] = *(const float4*)&sh.Vt[tx + j * 16][c];
        #pragma unroll
        for (int i = 0; i < 4; ++i)
            #pragma unroll
            for (int j = 0; j < 4; ++j)
                acco[i][j] += p4[i].x * vt4[j].x + p4[i].y * vt4[j].y +
                              p4[i].z * vt4[j].z + p4[i].w * vt4[j].w;
    }
    size_t base = ((size_t)b * cNS) * cH + hh * cDH;
    #pragma unroll
    for (int i = 0; i < 4; ++i)
        #pragma unroll
        for (int j = 0; j < 4; ++j)
            ctx_bf[base + (size_t)(ty * 4 + i) * cH + tx + j * 16] =
                __float2bfloat16(acco[i][j]);
}

// ---------------------------------------------------------------------------
// 3) O-GEMM + bias + GELU -> bf16 h.  Grid (24,8) = 192 blocks (wide: each
//    block pulls only a 49 KB W-slice; LN regressed at 32 blocks/full-W).
// ---------------------------------------------------------------------------
__global__ __launch_bounds__(256) void ogemm_kernel(
    const __hip_bfloat16* __restrict__ A,      // ctx_bf [M][H]
    const __hip_bfloat16* __restrict__ Wt,     // [H][H] n-major
    const float* __restrict__ bias,
    __hip_bfloat16* __restrict__ C)            // h bf16 [M][H]
{
    int lane = threadIdx.x & 63;
    int wave = threadIdx.x >> 6;
    int l15 = lane & 15, q4 = lane >> 4;
    int m0 = blockIdx.y * 64 + wave * 16;
    int n0 = blockIdx.x * 32;

    const __hip_bfloat16* Arow = A  + (size_t)(m0 + l15) * cH + q4 * 8;
    const __hip_bfloat16* Wr0  = Wt + (size_t)(n0 + l15) * cH + q4 * 8;
    const __hip_bfloat16* Wr1  = Wr0 + (size_t)16 * cH;

    f32x4 acc0 = {0.f, 0.f, 0.f, 0.f};
    f32x4 acc1 = {0.f, 0.f, 0.f, 0.f};
    #pragma unroll 8
    for (int k0 = 0; k0 < cH; k0 += 32) {
        bf16x8 a  = *(const bf16x8*)(Arow + k0);
        bf16x8 b0 = *(const bf16x8*)(Wr0 + k0);
        bf16x8 b1 = *(const bf16x8*)(Wr1 + k0);
        acc0 = __builtin_amdgcn_mfma_f32_16x16x32_bf16(a, b0, acc0, 0, 0, 0);
        acc1 = __builtin_amdgcn_mfma_f32_16x16x32_bf16(a, b1, acc1, 0, 0, 0);
    }
    #pragma unroll
    for (int nt = 0; nt < 2; ++nt) {
        const f32x4 acc = nt == 0 ? acc0 : acc1;
        int col = n0 + nt * 16 + l15;
        float bv = bias[col];
        #pragma unroll
        for (int r = 0; r < 4; ++r) {
            float v = acc[r] + bv;
            v = 0.5f * v * (1.0f + erff(v * 0.70710678118654752f));
            C[(size_t)(m0 + q4 * 4 + r) * cH + col] = __float2bfloat16(v);
        }
    }
}

// ---------------------------------------------------------------------------
// 4) LayerNorm over H=768 (bf16 input): writes bf16 x and optional f32 out.
//    512 blocks.
// ---------------------------------------------------------------------------
__global__ __launch_bounds__(256) void ln_kernel(
    const __hip_bfloat16* __restrict__ h, const float* __restrict__ g,
    const float* __restrict__ bb, __hip_bfloat16* __restrict__ xb,
    float* __restrict__ outf)
{
    int row = blockIdx.x;
    const __hip_bfloat16* r = h + (size_t)row * cH;
    int tid = threadIdx.x;
    float v0 = __bfloat162float(r[tid]);
    float v1 = __bfloat162float(r[tid + 256]);
    float v2 = __bfloat162float(r[tid + 512]);
    float s = v0 + v1 + v2;
    __shared__ float red[4];
    #pragma unroll
    for (int o = 32; o; o >>= 1) s += __shfl_xor(s, o);
    if ((tid & 63) == 0) red[tid >> 6] = s;
    __syncthreads();
    float mu = (red[0] + red[1] + red[2] + red[3]) * (1.0f / 768.0f);
    float d0 = v0 - mu, d1 = v1 - mu, d2 = v2 - mu;
    float ss = d0 * d0 + d1 * d1 + d2 * d2;
    __syncthreads();
    #pragma unroll
    for (int o = 32; o; o >>= 1) ss += __shfl_xor(ss, o);
    if ((tid & 63) == 0) red[tid >> 6] = ss;
    __syncthreads();
    float var = (red[0] + red[1] + red[2] + red[3]) * (1.0f / 768.0f);
    float inv = rsqrtf(var + 1e-12f);
    float o0 = d0 * inv * g[tid]       + bb[tid];
    float o1 = d1 * inv * g[tid + 256] + bb[tid + 256];
    float o2 = d2 * inv * g[tid + 512] + bb[tid + 512];
    __hip_bfloat16* xr = xb + (size_t)row * cH;
    xr[tid]       = __float2bfloat16(o0);
    xr[tid + 256] = __float2bfloat16(o1);
    xr[tid + 512] = __float2bfloat16(o2);
    if (outf) {
        float* orow = outf + (size_t)row * cH;
        orow[tid] = o0; orow[tid + 256] = o1; orow[tid + 512] = o2;
    }
}

// ---------------------------------------------------------------------------
extern "C" void kernel_launch(void* const* d_in, const int* in_sizes, int n_in,
                              void* d_out, int out_size, void* d_ws, size_t ws_size,
                              hipStream_t stream) {
    const int*   sent_ind = (const int*)d_in[0];
    const float* start    = (const float*)d_in[1];
    const float* Wq = (const float*)d_in[2];
    const float* bq = (const float*)d_in[3];
    const float* Wk = (const float*)d_in[4];
    const float* bk = (const float*)d_in[5];
    const float* Wv = (const float*)d_in[6];
    const float* bv = (const float*)d_in[7];
    const float* Wo = (const float*)d_in[8];
    const float* bo = (const float*)d_in[9];
    const float* ln_g = (const float*)d_in[10];
    const float* ln_b = (const float*)d_in[11];
    float* out = (float*)d_out;

    char* w = (char*)d_ws;
    __hip_bfloat16* wt     = (__hip_bfloat16*)w;                       // 8*H*H bf16
    __hip_bfloat16* x_bf   = (__hip_bfloat16*)(w + 9437184);           // M*H bf16
    __hip_bfloat16* ctx_bf = (__hip_bfloat16*)(w + 9437184 + 786432);  // M*H bf16
    __hip_bfloat16* hb     = (__hip_bfloat16*)(w + 9437184 + 2 * 786432); // M*H bf16

    prep_kernel<<<cM + 1152, 256, 0, stream>>>(sent_ind, start, x_bf,
                                               Wq, Wk, Wv, Wo, wt);

    for (int i = 0; i < cL; ++i) {
        const __hip_bfloat16* wqkv = wt + (size_t)(i * 4) * cH * cH;     // q,k,v contiguous
        const __hip_bfloat16* wto  = wt + (size_t)(i * 4 + 3) * cH * cH;
        qkvattn_kernel<<<cB * cNH, 256, 0, stream>>>(
            x_bf, wqkv, bq + (size_t)i * cH, bk + (size_t)i * cH, bv + (size_t)i * cH,
            ctx_bf);
        ogemm_kernel<<<dim3(24, 8), 256, 0, stream>>>(
            ctx_bf, wto, bo + (size_t)i * cH, hb);
        ln_kernel<<<cM, 256, 0, stream>>>(
            hb, ln_g + (size_t)i * cH, ln_b + (size_t)i * cH,
            x_bf, (i == cL - 1) ? out : nullptr);
    }
}

// Round 7
// 284.043 us; speedup vs baseline: 2.0997x; 1.0111x over previous
//
#include <hip/hip_runtime.h>
#include <hip/hip_bf16.h>

// Problem constants (match reference)
constexpr int cB  = 8;
constexpr int cS  = 4096;
constexpr int cH  = 768;
constexpr int cNH = 12;
constexpr int cL  = 2;
constexpr int cNS = 64;
constexpr int cDH = 64;
constexpr int cM  = cB * cNS;  // 512 rows of activations

typedef __attribute__((ext_vector_type(8))) short bf16x8;
typedef __attribute__((ext_vector_type(4))) float f32x4;

// ---------------------------------------------------------------------------
// 1) Fused prep (512 threads/block): blocks [0, 512) segment-mean pooling
//    (two 192-thread row-groups, 2x loads in flight, LDS combine);
//    blocks [512, 1088) weight transpose+convert, 2 tiles/block, per-lane
//    32 B contiguous bf16 stores (4 lanes = full 128 B row chunk).
// ---------------------------------------------------------------------------
union PrepShared {
    struct { int cnt; int list[cS]; float ps[192][4]; } p;   // 19.5 KB
    float T[2][64][65];                                      // 33.3 KB
};

__global__ __launch_bounds__(512) void prep_kernel(
    const int* __restrict__ sent_ind, const float* __restrict__ sl,
    __hip_bfloat16* __restrict__ xb,
    const float* __restrict__ Wq, const float* __restrict__ Wk,
    const float* __restrict__ Wv, const float* __restrict__ Wo,
    __hip_bfloat16* __restrict__ wt)
{
    __shared__ PrepShared sh;
    int tid = threadIdx.x;

    if (blockIdx.x < (unsigned)cM) {
        // ---------------- pool ----------------
        int bn = blockIdx.x;
        int b = bn >> 6, n = bn & (cNS - 1);
        if (tid == 0) sh.p.cnt = 0;
        __syncthreads();
        const int* si = sent_ind + (size_t)b * cS;
        for (int s = tid; s < cS; s += 512)
            if (s != 0 && si[s] == n) { int p = atomicAdd(&sh.p.cnt, 1); sh.p.list[p] = s; }
        __syncthreads();
        int c = sh.p.cnt;
        int grp = tid >> 8;          // 0 or 1: row-group
        int t   = tid & 255;
        int c0 = c >> 1;
        int lo = grp ? c0 : 0;
        int hi = grp ? c  : c0;
        float s0 = 0.f, s1 = 0.f, s2 = 0.f, s3 = 0.f;
        if (t < 192) {
            const float* bbase = sl + (size_t)b * cS * cH;
            int col = t * 4;
            float4 a0 = {0.f, 0.f, 0.f, 0.f};
            float4 a1 = {0.f, 0.f, 0.f, 0.f};
            float4 a2 = {0.f, 0.f, 0.f, 0.f};
            float4 a3 = {0.f, 0.f, 0.f, 0.f};
            int i = lo;
            for (; i + 4 <= hi; i += 4) {
                float4 r0 = *(const float4*)(bbase + (size_t)sh.p.list[i + 0] * cH + col);
                float4 r1 = *(const float4*)(bbase + (size_t)sh.p.list[i + 1] * cH + col);
                float4 r2 = *(const float4*)(bbase + (size_t)sh.p.list[i + 2] * cH + col);
                float4 r3 = *(const float4*)(bbase + (size_t)sh.p.list[i + 3] * cH + col);
                a0.x += r0.x; a0.y += r0.y; a0.z += r0.z; a0.w += r0.w;
                a1.x += r1.x; a1.y += r1.y; a1.z += r1.z; a1.w += r1.w;
                a2.x += r2.x; a2.y += r2.y; a2.z += r2.z; a2.w += r2.w;
                a3.x += r3.x; a3.y += r3.y; a3.z += r3.z; a3.w += r3.w;
            }
            for (; i < hi; ++i) {
                float4 r0 = *(const float4*)(bbase + (size_t)sh.p.list[i] * cH + col);
                a0.x += r0.x; a0.y += r0.y; a0.z += r0.z; a0.w += r0.w;
            }
            s0 = a0.x + a1.x + a2.x + a3.x;
            s1 = a0.y + a1.y + a2.y + a3.y;
            s2 = a0.z + a1.z + a2.z + a3.z;
            s3 = a0.w + a1.w + a2.w + a3.w;
        }
        if (grp == 1 && t < 192) {
            sh.p.ps[t][0] = s0; sh.p.ps[t][1] = s1;
            sh.p.ps[t][2] = s2; sh.p.ps[t][3] = s3;
        }
        __syncthreads();
        if (grp == 0 && t < 192) {
            float inv = 1.0f / (float)c;
            __hip_bfloat16* xr = xb + (size_t)bn * cH + t * 4;
            xr[0] = __float2bfloat16((s0 + sh.p.ps[t][0]) * inv);
            xr[1] = __float2bfloat16((s1 + sh.p.ps[t][1]) * inv);
            xr[2] = __float2bfloat16((s2 + sh.p.ps[t][2]) * inv);
            xr[3] = __float2bfloat16((s3 + sh.p.ps[t][3]) * inv);
        }
    } else {
        // ---------------- wconv: 2 tiles per block ----------------
        int sub = tid >> 8;                         // which tile
        int t   = tid & 255;
        int bi = (blockIdx.x - cM) * 2 + sub;       // 0..1151 = (12 x 12 x 8)
        int bx = bi % 12, by = (bi / 12) % 12, mat = bi / 144;
        int layer = mat >> 2, which = mat & 3;
        const float* W = (which == 0 ? Wq : which == 1 ? Wk : which == 2 ? Wv : Wo)
                         + (size_t)layer * cH * cH;
        int k0 = by * 64, n0 = bx * 64;
        int r = t >> 2, cb = (t & 3) * 16;
        #pragma unroll
        for (int u = 0; u < 4; ++u) {
            float4 w4 = *(const float4*)(W + (size_t)(k0 + r) * cH + n0 + cb + u * 4);
            sh.T[sub][r][cb + u * 4 + 0] = w4.x; sh.T[sub][r][cb + u * 4 + 1] = w4.y;
            sh.T[sub][r][cb + u * 4 + 2] = w4.z; sh.T[sub][r][cb + u * 4 + 3] = w4.w;
        }
        __syncthreads();
        // lane writes 16 bf16 = 32 B contiguous (two 16-B stores)
        int nn = t >> 2, kseg = (t & 3) * 16;
        __hip_bfloat16 tmp[16] __attribute__((aligned(16)));
        #pragma unroll
        for (int j = 0; j < 16; ++j)
            tmp[j] = __float2bfloat16(sh.T[sub][kseg + j][nn]);
        __hip_bfloat16* dst = wt + ((size_t)mat * cH + n0 + nn) * cH + k0 + kseg;
        *(bf16x8*)(dst)     = *(const bf16x8*)(tmp);
        *(bf16x8*)(dst + 8) = *(const bf16x8*)(tmp + 8);
    }
}

// ---------------------------------------------------------------------------
// 2) Fused qkv-GEMM + attention.  One block per (batch, head) = 96 blocks.
//    Block computes q,k,v [64 x 64] for its head via MFMA (K=768, weights
//    L2-resident, ~0.4 MB/block) straight into LDS, then runs attention.
//    Wave w: combos c = w*3+j -> (mat=c>>2, nt=c&3), all 4 m-tiles.
//    MFMA maps (m89/m91): a[j]=A[l15][q4*8+j], b[j]=Wt[l15][q4*8+j],
//    D: col=l15, row=q4*4+r.
// ---------------------------------------------------------------------------
struct AttnShared {
    float QP[cNS][cDH + 4];  // Q, later overlaid by P
    float Ks[cNS][cDH + 4];
    float Vt[cDH][cNS + 4];
};

__global__ __launch_bounds__(256) void qkvattn_kernel(
    const __hip_bfloat16* __restrict__ x_bf,
    const __hip_bfloat16* __restrict__ wqkv,   // [3][H][H] bf16 (n-major)
    const float* __restrict__ bq, const float* __restrict__ bk,
    const float* __restrict__ bv,
    __hip_bfloat16* __restrict__ ctx_bf)
{
    __shared__ AttnShared sh;
    int tid = threadIdx.x;
    int lane = tid & 63, wave = tid >> 6;
    int l15 = lane & 15, q4 = lane >> 4;
    int b = blockIdx.x / cNH, hh = blockIdx.x % cNH;

    const __hip_bfloat16* Arow[4];
    #pragma unroll
    for (int m = 0; m < 4; ++m)
        Arow[m] = x_bf + (size_t)(b * 64 + m * 16 + l15) * cH + q4 * 8;
    const __hip_bfloat16* Brow[3];
    int cmat[3], cnt_[3];
    #pragma unroll
    for (int j = 0; j < 3; ++j) {
        int c = wave * 3 + j;
        cmat[j] = c >> 2; cnt_[j] = c & 3;
        Brow[j] = wqkv + (size_t)cmat[j] * cH * cH
                       + (size_t)(hh * 64 + cnt_[j] * 16 + l15) * cH + q4 * 8;
    }

    f32x4 acc[3][4];
    #pragma unroll
    for (int j = 0; j < 3; ++j)
        #pragma unroll
        for (int m = 0; m < 4; ++m) acc[j][m] = (f32x4){0.f, 0.f, 0.f, 0.f};

    #pragma unroll 4
    for (int k0 = 0; k0 < cH; k0 += 32) {
        bf16x8 a[4], bb8[3];
        #pragma unroll
        for (int m = 0; m < 4; ++m) a[m] = *(const bf16x8*)(Arow[m] + k0);
        #pragma unroll
        for (int j = 0; j < 3; ++j) bb8[j] = *(const bf16x8*)(Brow[j] + k0);
        #pragma unroll
        for (int j = 0; j < 3; ++j)
            #pragma unroll
            for (int m = 0; m < 4; ++m)
                acc[j][m] = __builtin_amdgcn_mfma_f32_16x16x32_bf16(a[m], bb8[j], acc[j][m], 0, 0, 0);
    }

    const float scale = 0.125f;  // 1/sqrt(64)
    #pragma unroll
    for (int j = 0; j < 3; ++j) {
        int mat = cmat[j], nt = cnt_[j];
        int col_d = nt * 16 + l15;
        int col_g = hh * 64 + col_d;
        float bias = (mat == 0 ? bq : mat == 1 ? bk : bv)[col_g];
        #pragma unroll
        for (int m = 0; m < 4; ++m) {
            #pragma unroll
            for (int r = 0; r < 4; ++r) {
                int row_s = m * 16 + q4 * 4 + r;
                float v = acc[j][m][r] + bias;
                if (mat == 0)      sh.QP[row_s][col_d] = v * scale;
                else if (mat == 1) sh.Ks[row_s][col_d] = v;
                else               sh.Vt[col_d][row_s] = v;
            }
        }
    }
    __syncthreads();

    int tx = tid & 15, ty = tid >> 4;  // 16x16 threads, 4x4 microtiles
    float accs[4][4] = {};
    for (int d = 0; d < cDH; d += 4) {
        float4 qv[4], kv[4];
        #pragma unroll
        for (int i = 0; i < 4; ++i) qv[i] = *(const float4*)&sh.QP[ty * 4 + i][d];
        #pragma unroll
        for (int j = 0; j < 4; ++j) kv[j] = *(const float4*)&sh.Ks[tx + j * 16][d];
        #pragma unroll
        for (int i = 0; i < 4; ++i)
            #pragma unroll
            for (int j = 0; j < 4; ++j)
                accs[i][j] += qv[i].x * kv[j].x + qv[i].y * kv[j].y +
                              qv[i].z * kv[j].z + qv[i].w * kv[j].w;
    }
    __syncthreads();   // all QK^T reads done before P overlays Q
    #pragma unroll
    for (int i = 0; i < 4; ++i)
        #pragma unroll
        for (int j = 0; j < 4; ++j)
            sh.QP[ty * 4 + i][tx + j * 16] = accs[i][j];
    __syncthreads();

    {   // softmax: row = tid>>2, 16 cols/thread, quad shuffle
        int row = tid >> 2, jq = tid & 3;
        float e[16];
        float m = -1e30f;
        #pragma unroll
        for (int c = 0; c < 16; ++c) { e[c] = sh.QP[row][jq * 16 + c]; m = fmaxf(m, e[c]); }
        m = fmaxf(m, __shfl_xor(m, 1));
        m = fmaxf(m, __shfl_xor(m, 2));
        float s = 0.f;
        #pragma unroll
        for (int c = 0; c < 16; ++c) { e[c] = __expf(e[c] - m); s += e[c]; }
        s += __shfl_xor(s, 1);
        s += __shfl_xor(s, 2);
        float inv = 1.0f / s;
        #pragma unroll
        for (int c = 0; c < 16; ++c) sh.QP[row][jq * 16 + c] = e[c] * inv;
    }
    __syncthreads();

    float acco[4][4] = {};
    for (int c = 0; c < cNS; c += 4) {
        float4 p4[4], vt4[4];
        #pragma unroll
        for (int i = 0; i < 4; ++i) p4[i] = *(const float4*)&sh.QP[ty * 4 + i][c];
        #pragma unroll
        for (int j = 0; j < 4; ++j) vt4[j] = *(const float4*)&sh.Vt[tx + j * 16][c];
        #pragma unroll
        for (int i = 0; i < 4; ++i)
            #pragma unroll
            for (int j = 0; j < 4; ++j)
                acco[i][j] += p4[i].x * vt4[j].x + p4[i].y * vt4[j].y +
                              p4[i].z * vt4[j].z + p4[i].w * vt4[j].w;
    }
    size_t base = ((size_t)b * cNS) * cH + hh * cDH;
    #pragma unroll
    for (int i = 0; i < 4; ++i)
        #pragma unroll
        for (int j = 0; j < 4; ++j)
            ctx_bf[base + (size_t)(ty * 4 + i) * cH + tx + j * 16] =
                __float2bfloat16(acco[i][j]);
}

// ---------------------------------------------------------------------------
// 3) O-GEMM + bias + GELU -> bf16 h.  Grid (24,8) = 192 blocks (wide: each
//    block pulls only a 49 KB W-slice; LN-fused 32-block variant regressed).
// ---------------------------------------------------------------------------
__global__ __launch_bounds__(256) void ogemm_kernel(
    const __hip_bfloat16* __restrict__ A,      // ctx_bf [M][H]
    const __hip_bfloat16* __restrict__ Wt,     // [H][H] n-major
    const float* __restrict__ bias,
    __hip_bfloat16* __restrict__ C)            // h bf16 [M][H]
{
    int lane = threadIdx.x & 63;
    int wave = threadIdx.x >> 6;
    int l15 = lane & 15, q4 = lane >> 4;
    int m0 = blockIdx.y * 64 + wave * 16;
    int n0 = blockIdx.x * 32;

    const __hip_bfloat16* Arow = A  + (size_t)(m0 + l15) * cH + q4 * 8;
    const __hip_bfloat16* Wr0  = Wt + (size_t)(n0 + l15) * cH + q4 * 8;
    const __hip_bfloat16* Wr1  = Wr0 + (size_t)16 * cH;

    f32x4 acc0 = {0.f, 0.f, 0.f, 0.f};
    f32x4 acc1 = {0.f, 0.f, 0.f, 0.f};
    #pragma unroll 8
    for (int k0 = 0; k0 < cH; k0 += 32) {
        bf16x8 a  = *(const bf16x8*)(Arow + k0);
        bf16x8 b0 = *(const bf16x8*)(Wr0 + k0);
        bf16x8 b1 = *(const bf16x8*)(Wr1 + k0);
        acc0 = __builtin_amdgcn_mfma_f32_16x16x32_bf16(a, b0, acc0, 0, 0, 0);
        acc1 = __builtin_amdgcn_mfma_f32_16x16x32_bf16(a, b1, acc1, 0, 0, 0);
    }
    #pragma unroll
    for (int nt = 0; nt < 2; ++nt) {
        const f32x4 acc = nt == 0 ? acc0 : acc1;
        int col = n0 + nt * 16 + l15;
        float bv = bias[col];
        #pragma unroll
        for (int r = 0; r < 4; ++r) {
            float v = acc[r] + bv;
            v = 0.5f * v * (1.0f + erff(v * 0.70710678118654752f));
            C[(size_t)(m0 + q4 * 4 + r) * cH + col] = __float2bfloat16(v);
        }
    }
}

// ---------------------------------------------------------------------------
// 4) LayerNorm over H=768 (bf16 input): writes bf16 x and optional f32 out.
//    512 blocks.
// ---------------------------------------------------------------------------
__global__ __launch_bounds__(256) void ln_kernel(
    const __hip_bfloat16* __restrict__ h, const float* __restrict__ g,
    const float* __restrict__ bb, __hip_bfloat16* __restrict__ xb,
    float* __restrict__ outf)
{
    int row = blockIdx.x;
    const __hip_bfloat16* r = h + (size_t)row * cH;
    int tid = threadIdx.x;
    float v0 = __bfloat162float(r[tid]);
    float v1 = __bfloat162float(r[tid + 256]);
    float v2 = __bfloat162float(r[tid + 512]);
    float s = v0 + v1 + v2;
    __shared__ float red[4];
    #pragma unroll
    for (int o = 32; o; o >>= 1) s += __shfl_xor(s, o);
    if ((tid & 63) == 0) red[tid >> 6] = s;
    __syncthreads();
    float mu = (red[0] + red[1] + red[2] + red[3]) * (1.0f / 768.0f);
    float d0 = v0 - mu, d1 = v1 - mu, d2 = v2 - mu;
    float ss = d0 * d0 + d1 * d1 + d2 * d2;
    __syncthreads();
    #pragma unroll
    for (int o = 32; o; o >>= 1) ss += __shfl_xor(ss, o);
    if ((tid & 63) == 0) red[tid >> 6] = ss;
    __syncthreads();
    float var = (red[0] + red[1] + red[2] + red[3]) * (1.0f / 768.0f);
    float inv = rsqrtf(var + 1e-12f);
    float o0 = d0 * inv * g[tid]       + bb[tid];
    float o1 = d1 * inv * g[tid + 256] + bb[tid + 256];
    float o2 = d2 * inv * g[tid + 512] + bb[tid + 512];
    __hip_bfloat16* xr = xb + (size_t)row * cH;
    xr[tid]       = __float2bfloat16(o0);
    xr[tid + 256] = __float2bfloat16(o1);
    xr[tid + 512] = __float2bfloat16(o2);
    if (outf) {
        float* orow = outf + (size_t)row * cH;
        orow[tid] = o0; orow[tid + 256] = o1; orow[tid + 512] = o2;
    }
}

// ---------------------------------------------------------------------------
extern "C" void kernel_launch(void* const* d_in, const int* in_sizes, int n_in,
                              void* d_out, int out_size, void* d_ws, size_t ws_size,
                              hipStream_t stream) {
    const int*   sent_ind = (const int*)d_in[0];
    const float* start    = (const float*)d_in[1];
    const float* Wq = (const float*)d_in[2];
    const float* bq = (const float*)d_in[3];
    const float* Wk = (const float*)d_in[4];
    const float* bk = (const float*)d_in[5];
    const float* Wv = (const float*)d_in[6];
    const float* bv = (const float*)d_in[7];
    const float* Wo = (const float*)d_in[8];
    const float* bo = (const float*)d_in[9];
    const float* ln_g = (const float*)d_in[10];
    const float* ln_b = (const float*)d_in[11];
    float* out = (float*)d_out;

    char* w = (char*)d_ws;
    __hip_bfloat16* wt     = (__hip_bfloat16*)w;                       // 8*H*H bf16
    __hip_bfloat16* x_bf   = (__hip_bfloat16*)(w + 9437184);           // M*H bf16
    __hip_bfloat16* ctx_bf = (__hip_bfloat16*)(w + 9437184 + 786432);  // M*H bf16
    __hip_bfloat16* hb     = (__hip_bfloat16*)(w + 9437184 + 2 * 786432); // M*H bf16

    prep_kernel<<<cM + 576, 512, 0, stream>>>(sent_ind, start, x_bf,
                                              Wq, Wk, Wv, Wo, wt);

    for (int i = 0; i < cL; ++i) {
        const __hip_bfloat16* wqkv = wt + (size_t)(i * 4) * cH * cH;     // q,k,v contiguous
        const __hip_bfloat16* wto  = wt + (size_t)(i * 4 + 3) * cH * cH;
        qkvattn_kernel<<<cB * cNH, 256, 0, stream>>>(
            x_bf, wqkv, bq + (size_t)i * cH, bk + (size_t)i * cH, bv + (size_t)i * cH,
            ctx_bf);
        ogemm_kernel<<<dim3(24, 8), 256, 0, stream>>>(
            ctx_bf, wto, bo + (size_t)i * cH, hb);
        ln_kernel<<<cM, 256, 0, stream>>>(
            hb, ln_g + (size_t)i * cH, ln_b + (size_t)i * cH,
            x_bf, (i == cL - 1) ? out : nullptr);
    }
}